// Round 6
// baseline (14771.999 us; speedup 1.0000x reference)
//
#include <hip/hip_runtime.h>
#include <math.h>

// QuantumMambaSSMCore R6: TWO batches interleaved per wave (latency hiding).
//  - 64 blocks x 1 wave; each wave runs 2 independent batch scans -> their
//    serial latency windows (DPP/swizzle/bpermute, LDS reads, sincos, h chain)
//    overlap in the scheduler.
//  - Storage map per batch: regs r0..r3 = phys {2,4,6,8}; lanes L0..L5 =
//    phys {0,5,1,7,3,9}.  Phase C: 2 free / 10 DPP / 3 swizzle / 5 bpermute.
//  - Raw z stored per step (fire-and-forget); C*z + D*a applied by a parallel
//    post-kernel in-place on d_out.  Tables {th, cos(a*dt), sin(a*dt)} built
//    in a parallel prologue into 147 KB LDS.
//  - z-reduction: 3 DPP stages on 10 wires + cndmask pack + 1 swiz + 1 bperm.

#define PIF 3.14159265358979323846f

constexpr int NQ = 10, SEQ = 512, NBLK = 64, NTHR = 64, RECF = 36;

struct CTbl { int vu[2][NQ], mu[2][NQ], mz[4][NQ], vf[NQ], zm[NQ]; };

constexpr CTbl build_tbl() {
  CTbl t{};
  unsigned mrow[NQ], vcol[NQ];
  for (int b = 0; b < NQ; ++b) { mrow[b] = 1u << b; vcol[b] = 1u << b; }
  for (int d = 0; d < 4; ++d) {
    for (int i = 0; i < NQ; ++i) t.mz[d][i] = (int)mrow[9 - i];
    for (int i = 0; i < NQ - 1; ++i) {           // CNOT(i, i+1)
      int bc = 9 - i, bt = 8 - i;
      mrow[bt] ^= mrow[bc];
      vcol[bc] ^= vcol[bt];
    }
    { int bc = 0, bt = 9;                        // CNOT(9, 0)
      mrow[bt] ^= mrow[bc];
      vcol[bc] ^= vcol[bt]; }
  }
  for (int l = 0; l < 2; ++l) {
    for (int i = 0; i < NQ; ++i) { t.vu[l][i] = (int)vcol[9 - i]; t.mu[l][i] = (int)mrow[9 - i]; }
    for (int i = 0; i < NQ - 1; ++i) {
      int bc = 9 - i, bt = 8 - i;
      mrow[bt] ^= mrow[bc];
      vcol[bc] ^= vcol[bt];
    }
  }
  for (int i = 0; i < NQ; ++i) t.vf[i] = (int)vcol[9 - i];
  for (int i = 0; i < NQ; ++i) t.zm[i] = (int)mrow[9 - i];
  return t;
}
constexpr CTbl CT = build_tbl();

constexpr int regPart(int x)  { return ((x >> 2) & 1) | (((x >> 4) & 1) << 1) |
                                       (((x >> 6) & 1) << 2) | (((x >> 8) & 1) << 3); }
constexpr int lanePart(int x) { return ((x >> 0) & 1) | (((x >> 5) & 1) << 1) |
                                       (((x >> 1) & 1) << 2) | (((x >> 7) & 1) << 3) |
                                       (((x >> 3) & 1) << 4) | (((x >> 9) & 1) << 5); }

typedef __attribute__((ext_vector_type(2))) float v2;

// ---------------- cross-lane exchange helpers ----------------
template<int C>
__device__ __forceinline__ int dpp1(int x) {
  return __builtin_amdgcn_update_dpp(x, x, C, 0xF, 0xF, false);
}
template<int VL>
__device__ __forceinline__ int lxi(int x) {   // DPP xor-exchange, 1 <= VL <= 15
  if constexpr (VL == 1)  return dpp1<0xB1>(x);
  else if constexpr (VL == 2)  return dpp1<0x4E>(x);
  else if constexpr (VL == 3)  return dpp1<0x1B>(x);
  else if constexpr (VL <= 7) {
    constexpr int q = (VL & 3) ^ 3;
    int y = x;
    if constexpr (q == 1) y = dpp1<0xB1>(y);
    else if constexpr (q == 2) y = dpp1<0x4E>(y);
    else if constexpr (q == 3) y = dpp1<0x1B>(y);
    return dpp1<0x141>(y);                      // ^7
  } else if constexpr (VL >= 12) {
    constexpr int q = (VL & 3) ^ 3;
    int y = x;
    if constexpr (q == 1) y = dpp1<0xB1>(y);
    else if constexpr (q == 2) y = dpp1<0x4E>(y);
    else if constexpr (q == 3) y = dpp1<0x1B>(y);
    return dpp1<0x140>(y);                      // ^15
  } else {
    constexpr int a = VL & 3;
    int y = x;
    if constexpr (a == 1) y = dpp1<0xB1>(y);
    else if constexpr (a == 2) y = dpp1<0x4E>(y);
    else if constexpr (a == 3) y = dpp1<0x1B>(y);
    y = dpp1<0x141>(y);
    return dpp1<0x140>(y);
  }
}
template<int VL>
__device__ __forceinline__ float lx(float x) {
  if constexpr (VL == 0) return x;
  else if constexpr (VL & 32) {
    int addr = ((int)threadIdx.x ^ VL) << 2;
    return __int_as_float(__builtin_amdgcn_ds_bpermute(addr, __float_as_int(x)));
  } else if constexpr (VL & 16) {
    return __int_as_float(__builtin_amdgcn_ds_swizzle(__float_as_int(x), (VL << 10) | 0x1F));
  } else {
    return __int_as_float(lxi<VL>(__float_as_int(x)));
  }
}
__device__ __forceinline__ float rdl(float x, int l) {
  return __int_as_float(__builtin_amdgcn_readlane(__float_as_int(x), l));
}

// ---------------- gate: fused constant SU(2), both batches ----------------
template<int V, int M>
__device__ __forceinline__ void gate_u2(v2* a0, v2* a1, float4 U0, float4 U1, int lane) {
  constexpr int VL = lanePart(V), VR = regPart(V);
  constexpr int LM = lanePart(M), RM = regPart(M);
  v2 p0[16], p1[16];
#pragma unroll
  for (int r = 0; r < 16; ++r) {
    v2 s = a0[r ^ VR];
    p0[r].x = lx<VL>(s.x); p0[r].y = lx<VL>(s.y);
  }
#pragma unroll
  for (int r = 0; r < 16; ++r) {
    v2 s = a1[r ^ VR];
    p1[r].x = lx<VL>(s.x); p1[r].y = lx<VL>(s.y);
  }
  const bool plw = (__popc(lane & LM) & 1) != 0;
  v2 u00 = {U0.x, U0.y}, u01 = {U0.z, U0.w}, u10 = {U1.x, U1.y}, u11 = {U1.z, U1.w};
  v2 A0 = plw ? u11 : u00, B0 = plw ? u10 : u01;
  v2 A1 = plw ? u00 : u11, B1 = plw ? u01 : u10;
  v2 A0n = {-A0.y, A0.y}, B0n = {-B0.y, B0.y};
  v2 A1n = {-A1.y, A1.y}, B1n = {-B1.y, B1.y};
#pragma unroll
  for (int r = 0; r < 16; ++r) {
    const bool pr = (__popc(r & RM) & 1) != 0;
    v2 A = pr ? A1 : A0, An = pr ? A1n : A0n;
    v2 B = pr ? B1 : B0, Bn = pr ? B1n : B0n;
    v2 o = a0[r], q = p0[r];
    v2 res = A.x * o;
    res += An * __builtin_shufflevector(o, o, 1, 0);
    res += B.x * q;
    res += Bn * __builtin_shufflevector(q, q, 1, 0);
    a0[r] = res;
    o = a1[r]; q = p1[r];
    v2 res1 = A.x * o;
    res1 += An * __builtin_shufflevector(o, o, 1, 0);
    res1 += B.x * q;
    res1 += Bn * __builtin_shufflevector(q, q, 1, 0);
    a1[r] = res1;
  }
}

// ---------------- <X_w>: per-lane partial ----------------
template<int V>
__device__ __forceinline__ float xdot(const v2* amp) {
  constexpr int VL = lanePart(V), VR = regPart(V);
  v2 acc = {0.f, 0.f};
#pragma unroll
  for (int r = 0; r < 16; ++r) {
    v2 s = amp[r ^ VR];
    v2 p; p.x = lx<VL>(s.x); p.y = lx<VL>(s.y);
    acc += amp[r] * p;
  }
  return acc.x + acc.y;
}

// ---------------- main kernel: one wave, two batches ----------------
__global__ __launch_bounds__(NTHR, 1) void qmamba_main(
    const float* __restrict__ angles, const float* __restrict__ Wx,
    const float* __restrict__ Wdt, const float* __restrict__ bdt,
    const float* __restrict__ pc, const float* __restrict__ cp,
    float* __restrict__ out)
{
  __shared__ float  tblL[2][SEQ][RECF];   // 147456 B: th[0..9], cf[12..21], sf[24..33]
  __shared__ float4 uuL[40];              // 640 B

  const int lane = threadIdx.x;
  const int blk  = blockIdx.x;

  // prologue 1: fused variational unitaries
  if (lane < 20) {
    int k = lane * 3;
    float al = 0.5f * cp[k], be = 0.5f * cp[k + 1], ga = 0.5f * cp[k + 2];
    float ca = __cosf(al), sa = __sinf(al);
    float cb = __cosf(be), sb = __sinf(be);
    float cg = __cosf(ga), sg = __sinf(ga);
    float2 M00 = make_float2(cb * ca,  sb * sa);
    float2 M01 = make_float2(-sb * ca, -cb * sa);
    float2 M10 = make_float2(sb * ca,  -cb * sa);
    float2 M11 = make_float2(cb * ca,  -sb * sa);
    float2 e0 = make_float2(cg, -sg), e1 = make_float2(cg, sg);
    auto cm = [](float2 a, float2 c) {
      return make_float2(a.x * c.x - a.y * c.y, a.x * c.y + a.y * c.x);
    };
    float2 u00 = cm(M00, e0), u01 = cm(M01, e0), u10 = cm(M10, e1), u11 = cm(M11, e1);
    uuL[2 * lane]     = make_float4(u00.x, u00.y, u01.x, u01.y);
    uuL[2 * lane + 1] = make_float4(u10.x, u10.y, u11.x, u11.y);
  }

  // prologue 2: per-step tables for BOTH batches (each lane: 16 records)
#pragma unroll 1
  for (int k = 0; k < 16; ++k) {
    const int idx = k * 64 + lane;          // 0..1023
    const int bb  = idx >> 9, t = idx & 511;
    const float* ar = angles + (size_t)((2 * blk + bb) * SEQ + t) * NQ;
    float a[NQ];
#pragma unroll
    for (int n = 0; n < NQ; ++n) a[n] = ar[n];
    float dtr[5];
#pragma unroll
    for (int r = 0; r < 5; ++r) {
      float acc = 0.f;
#pragma unroll
      for (int n = 0; n < NQ; ++n) acc += a[n] * Wx[r * NQ + n];
      dtr[r] = acc;
    }
    float* rec = &tblL[bb][t][0];
#pragma unroll
    for (int w = 0; w < NQ; ++w) {
      float lin = bdt[w];
#pragma unroll
      for (int r = 0; r < 5; ++r) lin += dtr[r] * Wdt[w * 5 + r];
      float sp = lin > 0.f ? lin + log1pf(__expf(-lin)) : log1pf(__expf(lin));
      float th = tanhf(sp) * PIF;
      float fa = a[w] * th;
      rec[w]      = th;
      rec[12 + w] = __cosf(fa);
      rec[24 + w] = __sinf(fa);
    }
  }
  __syncthreads();

  float pch[4];
#pragma unroll
  for (int d = 0; d < 4; ++d) pch[d] = 0.5f * pc[d] * PIF;

  unsigned PW0 = 0, PW1 = 0;
#pragma unroll
  for (int k = 0; k < 40; ++k) {
    const int lm = lanePart(CT.mz[k / 10][k % 10]);
    unsigned flip = (__popc(lane & lm) & 1) ^ 1;
    if (k < 32) PW0 |= flip << k; else PW1 |= flip << (k - 32);
  }

  float hc0[NQ], hs0[NQ], hc1[NQ], hs1[NQ];
#pragma unroll
  for (int w = 0; w < NQ; ++w) { hc0[w] = 1.f; hs0[w] = 0.f; hc1[w] = 1.f; hs1[w] = 0.f; }

  v2 amp0[16], amp1[16];

#pragma unroll 1
  for (int t = 0; t < SEQ; ++t) {
    // amp init (Phase A * Phase B) for one batch
    auto init_amp = [&](v2* amp, const float* hc, const float* hs, const float* th) {
      float F;
      F  = (lane & 1)  ? hs[9] : hc[9];
      F *= (lane & 2)  ? hs[4] : hc[4];
      F *= (lane & 4)  ? hs[8] : hc[8];
      F *= (lane & 8)  ? hs[2] : hc[2];
      F *= (lane & 16) ? hs[6] : hc[6];
      F *= (lane & 32) ? hs[0] : hc[0];
      float G[16];
      {
        float g01[4], g23[4];
        g01[0] = hc[7] * hc[5]; g01[1] = hs[7] * hc[5];
        g01[2] = hc[7] * hs[5]; g01[3] = hs[7] * hs[5];
        g23[0] = hc[3] * hc[1]; g23[1] = hs[3] * hc[1];
        g23[2] = hc[3] * hs[1]; g23[3] = hs[3] * hs[1];
#pragma unroll
        for (int r = 0; r < 16; ++r) G[r] = F * g01[r & 3] * g23[(r >> 2) & 3];
      }
      float S[16];
#pragma unroll
      for (int g = 0; g < 16; ++g) S[g] = 0.f;
#pragma unroll
      for (int k = 0; k < 40; ++k) {
        const int m  = CT.mz[k / 10][k % 10];
        const int gr = regPart(m);
        float v = pch[k / 10] * th[k % 10];
        unsigned fl = ((k < 32 ? (PW0 >> k) : (PW1 >> (k - 32))) & 1u) << 31;
        S[gr] += __int_as_float(__float_as_int(v) ^ fl);
      }
#pragma unroll
      for (int bb = 1; bb < 16; bb <<= 1) {
#pragma unroll
        for (int g = 0; g < 16; ++g)
          if (!(g & bb)) { float x = S[g], y = S[g | bb]; S[g] = x + y; S[g | bb] = x - y; }
      }
#pragma unroll
      for (int r = 0; r < 16; ++r) {
        float sn, cs;
        __sincosf(S[r], &sn, &cs);
        amp[r].x = G[r] * cs;
        amp[r].y = G[r] * sn;
      }
    };

    {
      float tha[12], thb[12];
      const float4* r0 = (const float4*)&tblL[0][t][0];
      const float4* r1 = (const float4*)&tblL[1][t][0];
#pragma unroll
      for (int j = 0; j < 3; ++j) { ((float4*)tha)[j] = r0[j]; ((float4*)thb)[j] = r1[j]; }
      init_amp(amp0, hc0, hs0, tha);
      init_amp(amp1, hc1, hs1, thb);
    }

    // Phase C: 20 fused SU(2) gates on both batches
#define GU(L, I, G_) gate_u2<CT.vu[L][I], CT.mu[L][I]>(amp0, amp1, uuL[2*(G_)], uuL[2*(G_)+1], lane);
    GU(0, 0, 0)  GU(0, 1, 1)  GU(0, 2, 2)  GU(0, 3, 3)  GU(0, 4, 4)
    GU(0, 5, 5)  GU(0, 6, 6)  GU(0, 7, 7)  GU(0, 8, 8)  GU(0, 9, 9)
    GU(1, 0, 10) GU(1, 1, 11) GU(1, 2, 12) GU(1, 3, 13) GU(1, 4, 14)
    GU(1, 5, 15) GU(1, 6, 16) GU(1, 7, 17) GU(1, 8, 18) GU(1, 9, 19)
#undef GU

    // measurement for one batch -> zsel (lane w holds z_w for w<10)
    auto measure = [&](const v2* amp, const float* cf, const float* sf) -> float {
      float T[16];
#pragma unroll
      for (int r = 0; r < 16; ++r) T[r] = amp[r].x * amp[r].x + amp[r].y * amp[r].y;
#pragma unroll
      for (int bb = 1; bb < 16; bb <<= 1) {
#pragma unroll
        for (int g = 0; g < 16; ++g)
          if (!(g & bb)) { float x = T[g], y = T[g | bb]; T[g] = x + y; T[g | bb] = x - y; }
      }
      float zv[NQ];
#define MEAS(W) {                                                   \
        constexpr int zmv = CT.zm[W];                               \
        float zp = T[regPart(zmv)];                                 \
        if (__popc(lane & lanePart(zmv)) & 1) zp = -zp;             \
        float xp = xdot<CT.vf[W]>(amp);                             \
        zv[W] = cf[W] * zp - sf[W] * xp;                            \
      }
      MEAS(0) MEAS(1) MEAS(2) MEAS(3) MEAS(4)
      MEAS(5) MEAS(6) MEAS(7) MEAS(8) MEAS(9)
#undef MEAS
      // 3 DPP butterfly stages on all wires
#pragma unroll
      for (int w = 0; w < NQ; ++w) {
        zv[w] += lx<1>(zv[w]);
        zv[w] += lx<2>(zv[w]);
        zv[w] += lx<4>(zv[w]);
      }
      // pack wire (lane&7), finish with xor8/16/32
      const int l7 = lane & 7;
      float c01 = (l7 & 1) ? zv[1] : zv[0];
      float c23 = (l7 & 1) ? zv[3] : zv[2];
      float c45 = (l7 & 1) ? zv[5] : zv[4];
      float c67 = (l7 & 1) ? zv[7] : zv[6];
      float c03 = (l7 & 2) ? c23 : c01;
      float c47 = (l7 & 2) ? c67 : c45;
      float pk  = (l7 & 4) ? c47 : c03;
      pk += lx<8>(pk);  pk += lx<16>(pk);  pk += lx<32>(pk);
      float z8 = zv[8]; z8 += lx<8>(z8); z8 += lx<16>(z8); z8 += lx<32>(z8);
      float z9 = zv[9]; z9 += lx<8>(z9); z9 += lx<16>(z9); z9 += lx<32>(z9);
      float zs = pk;
      zs = (lane == 8) ? z8 : zs;
      zs = (lane == 9) ? z9 : zs;
      return zs;
    };

    float cf0a[12], sf0a[12], cf1a[12], sf1a[12];
    {
      const float4* r0 = (const float4*)&tblL[0][t][0];
      const float4* r1 = (const float4*)&tblL[1][t][0];
#pragma unroll
      for (int j = 0; j < 3; ++j) {
        ((float4*)cf0a)[j] = r0[3 + j]; ((float4*)sf0a)[j] = r0[6 + j];
        ((float4*)cf1a)[j] = r1[3 + j]; ((float4*)sf1a)[j] = r1[6 + j];
      }
    }
    float zs0 = measure(amp0, cf0a, sf0a);
    float zs1 = measure(amp1, cf1a, sf1a);

    // store raw z (fire-and-forget; post-kernel applies C*z + D*a)
    if (lane < NQ) {
      out[((size_t)((2 * blk + 0) * SEQ) + t) * NQ + lane] = zs0;
      out[((size_t)((2 * blk + 1) * SEQ) + t) * NQ + lane] = zs1;
    }

    // h update for next step
    float sn0, cs0_, sn1, cs1_;
    __sincosf(0.5f * zs0, &sn0, &cs0_);
    __sincosf(0.5f * zs1, &sn1, &cs1_);
#pragma unroll
    for (int w = 0; w < NQ; ++w) {
      hc0[w] = rdl(cs0_, w); hs0[w] = rdl(sn0, w);
      hc1[w] = rdl(cs1_, w); hs1[w] = rdl(sn1, w);
    }
  }
}

// ---------------- post kernel: out = C*z + D*a, in place ----------------
__global__ __launch_bounds__(256) void qmamba_post(
    const float* __restrict__ angles, const float* __restrict__ Wx,
    const float* __restrict__ Dg, float* __restrict__ out)
{
  int i = blockIdx.x * 256 + threadIdx.x;          // 0 .. 128*512*10-1
  if (i >= 128 * SEQ * NQ) return;
  int w  = i % NQ;
  int bt = i / NQ;
  const float* a = angles + (size_t)bt * NQ;
  float C = 0.f;
#pragma unroll
  for (int n = 0; n < NQ; ++n) C += a[n] * Wx[(15 + w) * NQ + n];
  float z = out[i];
  out[i] = C * z + Dg[w] * a[w];
}

extern "C" void kernel_launch(void* const* d_in, const int* in_sizes, int n_in,
                              void* d_out, int out_size, void* d_ws, size_t ws_size,
                              hipStream_t stream) {
  (void)in_sizes; (void)n_in; (void)out_size; (void)d_ws; (void)ws_size;
  const float* angles = (const float*)d_in[0];
  const float* Wx     = (const float*)d_in[1];
  const float* Wdt    = (const float*)d_in[2];
  const float* bdt    = (const float*)d_in[3];
  const float* pc     = (const float*)d_in[4];
  const float* cp     = (const float*)d_in[5];
  const float* Dg     = (const float*)d_in[6];
  float* out = (float*)d_out;
  hipLaunchKernelGGL(qmamba_main, dim3(NBLK), dim3(NTHR), 0, stream,
                     angles, Wx, Wdt, bdt, pc, cp, out);
  hipLaunchKernelGGL(qmamba_post, dim3((128 * SEQ * NQ + 255) / 256), dim3(256), 0, stream,
                     angles, Wx, Dg, out);
}

// Round 7
// 4927.602 us; speedup vs baseline: 2.9978x; 2.9978x over previous
//
#include <hip/hip_runtime.h>
#include <math.h>

// QuantumMambaSSMCore R7: R5 single-wave zero-barrier scan, register-pressure
// crushed to eliminate scratch spills (R4/R5 were pegged at VGPR 252-256).
//  - 1 wave/block, 128 blocks, 16 amps/thread (v2 = complex).
//  - Storage map: regs r0..r3 = phys {2,4,6,8}; lanes L0..L5 = phys {0,5,1,7,3,9}.
//  - Per-step tables {th, cos(a*dt), sin(a*dt)} in 74 KB LDS (parallel prologue).
//    th loaded at loop-top (transient), cf/sf loaded just before measurement.
//  - Raw z stored fire-and-forget; C*z + D*a applied by parallel post-kernel.
//  - Measurement: 3 shared DPP stages + cndmask pack + 3 stages (lane w -> z_w).

#define PIF 3.14159265358979323846f

constexpr int NQ = 10, SEQ = 512, NB = 128, NTHR = 64, RECF = 36;

struct CTbl { int vu[2][NQ], mu[2][NQ], mz[4][NQ], vf[NQ], zm[NQ]; };

constexpr CTbl build_tbl() {
  CTbl t{};
  unsigned mrow[NQ], vcol[NQ];
  for (int b = 0; b < NQ; ++b) { mrow[b] = 1u << b; vcol[b] = 1u << b; }
  for (int d = 0; d < 4; ++d) {
    for (int i = 0; i < NQ; ++i) t.mz[d][i] = (int)mrow[9 - i];
    for (int i = 0; i < NQ - 1; ++i) {           // CNOT(i, i+1)
      int bc = 9 - i, bt = 8 - i;
      mrow[bt] ^= mrow[bc];
      vcol[bc] ^= vcol[bt];
    }
    { int bc = 0, bt = 9;                        // CNOT(9, 0)
      mrow[bt] ^= mrow[bc];
      vcol[bc] ^= vcol[bt]; }
  }
  for (int l = 0; l < 2; ++l) {
    for (int i = 0; i < NQ; ++i) { t.vu[l][i] = (int)vcol[9 - i]; t.mu[l][i] = (int)mrow[9 - i]; }
    for (int i = 0; i < NQ - 1; ++i) {
      int bc = 9 - i, bt = 8 - i;
      mrow[bt] ^= mrow[bc];
      vcol[bc] ^= vcol[bt];
    }
  }
  for (int i = 0; i < NQ; ++i) t.vf[i] = (int)vcol[9 - i];
  for (int i = 0; i < NQ; ++i) t.zm[i] = (int)mrow[9 - i];
  return t;
}
constexpr CTbl CT = build_tbl();

constexpr int regPart(int x)  { return ((x >> 2) & 1) | (((x >> 4) & 1) << 1) |
                                       (((x >> 6) & 1) << 2) | (((x >> 8) & 1) << 3); }
constexpr int lanePart(int x) { return ((x >> 0) & 1) | (((x >> 5) & 1) << 1) |
                                       (((x >> 1) & 1) << 2) | (((x >> 7) & 1) << 3) |
                                       (((x >> 3) & 1) << 4) | (((x >> 9) & 1) << 5); }

typedef __attribute__((ext_vector_type(2))) float v2;

// ---------------- cross-lane exchange helpers ----------------
template<int C>
__device__ __forceinline__ int dpp1(int x) {
  return __builtin_amdgcn_update_dpp(x, x, C, 0xF, 0xF, false);
}
template<int VL>
__device__ __forceinline__ int lxi(int x) {   // DPP xor-exchange, 1 <= VL <= 15
  if constexpr (VL == 1)  return dpp1<0xB1>(x);
  else if constexpr (VL == 2)  return dpp1<0x4E>(x);
  else if constexpr (VL == 3)  return dpp1<0x1B>(x);
  else if constexpr (VL <= 7) {
    constexpr int q = (VL & 3) ^ 3;
    int y = x;
    if constexpr (q == 1) y = dpp1<0xB1>(y);
    else if constexpr (q == 2) y = dpp1<0x4E>(y);
    else if constexpr (q == 3) y = dpp1<0x1B>(y);
    return dpp1<0x141>(y);                      // ^7
  } else if constexpr (VL >= 12) {
    constexpr int q = (VL & 3) ^ 3;
    int y = x;
    if constexpr (q == 1) y = dpp1<0xB1>(y);
    else if constexpr (q == 2) y = dpp1<0x4E>(y);
    else if constexpr (q == 3) y = dpp1<0x1B>(y);
    return dpp1<0x140>(y);                      // ^15
  } else {
    constexpr int a = VL & 3;
    int y = x;
    if constexpr (a == 1) y = dpp1<0xB1>(y);
    else if constexpr (a == 2) y = dpp1<0x4E>(y);
    else if constexpr (a == 3) y = dpp1<0x1B>(y);
    y = dpp1<0x141>(y);
    return dpp1<0x140>(y);
  }
}
template<int VL>
__device__ __forceinline__ float lx(float x) {
  if constexpr (VL == 0) return x;
  else if constexpr (VL & 32) {
    int addr = ((int)threadIdx.x ^ VL) << 2;
    return __int_as_float(__builtin_amdgcn_ds_bpermute(addr, __float_as_int(x)));
  } else if constexpr (VL & 16) {
    return __int_as_float(__builtin_amdgcn_ds_swizzle(__float_as_int(x), (VL << 10) | 0x1F));
  } else {
    return __int_as_float(lxi<VL>(__float_as_int(x)));
  }
}
__device__ __forceinline__ float rdl(float x, int l) {
  return __int_as_float(__builtin_amdgcn_readlane(__float_as_int(x), l));
}

// ---------------- gate: fused constant SU(2), preloaded U ----------------
template<int V, int M>
__device__ __forceinline__ void gate_u(v2* amp, float4 U0, float4 U1, int lane) {
  constexpr int VL = lanePart(V), VR = regPart(V);
  constexpr int LM = lanePart(M), RM = regPart(M);
  v2 p[16];
#pragma unroll
  for (int r = 0; r < 16; ++r) {
    v2 s = amp[r ^ VR];
    p[r].x = lx<VL>(s.x);
    p[r].y = lx<VL>(s.y);
  }
  const bool plw = (__popc(lane & LM) & 1) != 0;
  v2 u00 = {U0.x, U0.y}, u01 = {U0.z, U0.w}, u10 = {U1.x, U1.y}, u11 = {U1.z, U1.w};
  v2 A0 = plw ? u11 : u00, B0 = plw ? u10 : u01;
  v2 A1 = plw ? u00 : u11, B1 = plw ? u01 : u10;
  v2 A0n = {-A0.y, A0.y}, B0n = {-B0.y, B0.y};
  v2 A1n = {-A1.y, A1.y}, B1n = {-B1.y, B1.y};
#pragma unroll
  for (int r = 0; r < 16; ++r) {
    const bool pr = (__popc(r & RM) & 1) != 0;
    v2 A = pr ? A1 : A0, An = pr ? A1n : A0n;
    v2 B = pr ? B1 : B0, Bn = pr ? B1n : B0n;
    v2 o = amp[r], q = p[r];
    v2 res = A.x * o;
    res += An * __builtin_shufflevector(o, o, 1, 0);
    res += B.x * q;
    res += Bn * __builtin_shufflevector(q, q, 1, 0);
    amp[r] = res;
  }
}

// ---------------- <X_w>: per-lane partial ----------------
template<int V>
__device__ __forceinline__ float xdot(const v2* amp) {
  constexpr int VL = lanePart(V), VR = regPart(V);
  v2 acc = {0.f, 0.f};
#pragma unroll
  for (int r = 0; r < 16; ++r) {
    v2 s = amp[r ^ VR];
    v2 p; p.x = lx<VL>(s.x); p.y = lx<VL>(s.y);
    acc += amp[r] * p;
  }
  return acc.x + acc.y;
}

// ---------------- main kernel: one wave per batch element ----------------
__global__ __launch_bounds__(NTHR, 1) void qmamba_main(
    const float* __restrict__ angles, const float* __restrict__ Wx,
    const float* __restrict__ Wdt, const float* __restrict__ bdt,
    const float* __restrict__ pc, const float* __restrict__ cp,
    float* __restrict__ out)
{
  __shared__ float  tblL[SEQ][RECF];   // 73728 B: th @0..9, cf @12..21, sf @24..33
  __shared__ float4 uuL[40];           // 640 B

  const int lane = threadIdx.x;
  const int b    = blockIdx.x;

  // prologue 1: fused variational unitaries U = RZ(g)*RY(be)*RX(al)
  if (lane < 20) {
    int k = lane * 3;
    float al = 0.5f * cp[k], be = 0.5f * cp[k + 1], ga = 0.5f * cp[k + 2];
    float ca = __cosf(al), sa = __sinf(al);
    float cb = __cosf(be), sb = __sinf(be);
    float cg = __cosf(ga), sg = __sinf(ga);
    float2 M00 = make_float2(cb * ca,  sb * sa);
    float2 M01 = make_float2(-sb * ca, -cb * sa);
    float2 M10 = make_float2(sb * ca,  -cb * sa);
    float2 M11 = make_float2(cb * ca,  -sb * sa);
    float2 e0 = make_float2(cg, -sg), e1 = make_float2(cg, sg);
    auto cm = [](float2 a, float2 c) {
      return make_float2(a.x * c.x - a.y * c.y, a.x * c.y + a.y * c.x);
    };
    float2 u00 = cm(M00, e0), u01 = cm(M01, e0), u10 = cm(M10, e1), u11 = cm(M11, e1);
    uuL[2 * lane]     = make_float4(u00.x, u00.y, u01.x, u01.y);
    uuL[2 * lane + 1] = make_float4(u10.x, u10.y, u11.x, u11.y);
  }

  // prologue 2: per-step tables (each lane computes 8 steps)
#pragma unroll 1
  for (int k = 0; k < 8; ++k) {
    const int t = k * 64 + lane;
    const float* ar = angles + (size_t)(b * SEQ + t) * NQ;
    float a[NQ];
#pragma unroll
    for (int n = 0; n < NQ; ++n) a[n] = ar[n];
    float dtr[5];
#pragma unroll
    for (int r = 0; r < 5; ++r) {
      float acc = 0.f;
#pragma unroll
      for (int n = 0; n < NQ; ++n) acc += a[n] * Wx[r * NQ + n];
      dtr[r] = acc;
    }
    float* rec = &tblL[t][0];
#pragma unroll
    for (int w = 0; w < NQ; ++w) {
      float lin = bdt[w];
#pragma unroll
      for (int r = 0; r < 5; ++r) lin += dtr[r] * Wdt[w * 5 + r];
      float sp = lin > 0.f ? lin + log1pf(__expf(-lin)) : log1pf(__expf(lin));
      float th = tanhf(sp) * PIF;
      float fa = a[w] * th;
      rec[w]      = th;
      rec[12 + w] = __cosf(fa);
      rec[24 + w] = __sinf(fa);
    }
  }
  __syncthreads();   // single wave: one-time

  float pch[4];
#pragma unroll
  for (int d = 0; d < 4; ++d) pch[d] = 0.5f * pc[d] * PIF;

  unsigned PW0 = 0, PW1 = 0;
#pragma unroll
  for (int k = 0; k < 40; ++k) {
    const int lm = lanePart(CT.mz[k / 10][k % 10]);
    unsigned flip = (__popc(lane & lm) & 1) ^ 1;
    if (k < 32) PW0 |= flip << k; else PW1 |= flip << (k - 32);
  }

  float hcw[NQ], hsw[NQ];
#pragma unroll
  for (int w = 0; w < NQ; ++w) { hcw[w] = 1.f; hsw[w] = 0.f; }

  v2 amp[16];

#pragma unroll 1
  for (int t = 0; t < SEQ; ++t) {
    // ---- th table (transient: dies at end of Phase B)
    float tha[12];
    {
      const float4* rq = (const float4*)&tblL[t][0];
#pragma unroll
      for (int j = 0; j < 3; ++j) ((float4*)tha)[j] = rq[j];
    }

    // ---- Phase A: real product state from RY(h)|0>
    // lanes: L0=w9 L1=w4 L2=w8 L3=w2 L4=w6 L5=w0; regs: r0=w7 r1=w5 r2=w3 r3=w1
    float F;
    F  = (lane & 1)  ? hsw[9] : hcw[9];
    F *= (lane & 2)  ? hsw[4] : hcw[4];
    F *= (lane & 4)  ? hsw[8] : hcw[8];
    F *= (lane & 8)  ? hsw[2] : hcw[2];
    F *= (lane & 16) ? hsw[6] : hcw[6];
    F *= (lane & 32) ? hsw[0] : hcw[0];
    float G[16];
    {
      float g01[4], g23[4];
      g01[0] = hcw[7] * hcw[5]; g01[1] = hsw[7] * hcw[5];
      g01[2] = hcw[7] * hsw[5]; g01[3] = hsw[7] * hsw[5];
      g23[0] = hcw[3] * hcw[1]; g23[1] = hsw[3] * hcw[1];
      g23[2] = hcw[3] * hsw[1]; g23[3] = hsw[3] * hsw[1];
#pragma unroll
      for (int r = 0; r < 16; ++r) G[r] = F * g01[r & 3] * g23[(r >> 2) & 3];
    }

    // ---- Phase B: fused 40-RZ phase
    float S[16];
#pragma unroll
    for (int g = 0; g < 16; ++g) S[g] = 0.f;
#pragma unroll
    for (int k = 0; k < 40; ++k) {
      const int m  = CT.mz[k / 10][k % 10];
      const int gr = regPart(m);
      float v = pch[k / 10] * tha[k % 10];
      unsigned fl = ((k < 32 ? (PW0 >> k) : (PW1 >> (k - 32))) & 1u) << 31;
      S[gr] += __int_as_float(__float_as_int(v) ^ fl);
    }
#pragma unroll
    for (int bb = 1; bb < 16; bb <<= 1) {
#pragma unroll
      for (int g = 0; g < 16; ++g)
        if (!(g & bb)) { float x = S[g], y = S[g | bb]; S[g] = x + y; S[g | bb] = x - y; }
    }
#pragma unroll
    for (int r = 0; r < 16; ++r) {
      float sn, cs;
      __sincosf(S[r], &sn, &cs);
      amp[r].x = G[r] * cs;
      amp[r].y = G[r] * sn;
    }

    // ---- Phase C: 20 fused SU(2) gates
#define GU(L, I, G_) gate_u<CT.vu[L][I], CT.mu[L][I]>(amp, uuL[2*(G_)], uuL[2*(G_)+1], lane);
    GU(0, 0, 0)  GU(0, 1, 1)  GU(0, 2, 2)  GU(0, 3, 3)  GU(0, 4, 4)
    GU(0, 5, 5)  GU(0, 6, 6)  GU(0, 7, 7)  GU(0, 8, 8)  GU(0, 9, 9)
    GU(1, 0, 10) GU(1, 1, 11) GU(1, 2, 12) GU(1, 3, 13) GU(1, 4, 14)
    GU(1, 5, 15) GU(1, 6, 16) GU(1, 7, 17) GU(1, 8, 18) GU(1, 9, 19)
#undef GU

    // ---- cf/sf tables (transient: loaded only now)
    float cfv[12], sfv[12];
    {
      const float4* rq = (const float4*)&tblL[t][0];
#pragma unroll
      for (int j = 0; j < 3; ++j) { ((float4*)cfv)[j] = rq[3 + j]; ((float4*)sfv)[j] = rq[6 + j]; }
    }

    // ---- measurement with fused final-RY: z_w = cos*<Z_w> - sin*<X_w>
    float T[16];
#pragma unroll
    for (int r = 0; r < 16; ++r) T[r] = amp[r].x * amp[r].x + amp[r].y * amp[r].y;
#pragma unroll
    for (int bb = 1; bb < 16; bb <<= 1) {
#pragma unroll
      for (int g = 0; g < 16; ++g)
        if (!(g & bb)) { float x = T[g], y = T[g | bb]; T[g] = x + y; T[g | bb] = x - y; }
    }
    float zv[NQ];
#define MEAS(W) {                                                   \
      constexpr int zmv = CT.zm[W];                                 \
      float zp = T[regPart(zmv)];                                   \
      if (__popc(lane & lanePart(zmv)) & 1) zp = -zp;               \
      float xp = xdot<CT.vf[W]>(amp);                               \
      zv[W] = cfv[W] * zp - sfv[W] * xp;                            \
    }
    MEAS(0) MEAS(1) MEAS(2) MEAS(3) MEAS(4)
    MEAS(5) MEAS(6) MEAS(7) MEAS(8) MEAS(9)
#undef MEAS

    // 3 shared DPP stages, pack by lane&7, 3 more stages -> lane w holds z_w
#pragma unroll
    for (int w = 0; w < NQ; ++w) {
      zv[w] += lx<1>(zv[w]);
      zv[w] += lx<2>(zv[w]);
      zv[w] += lx<4>(zv[w]);
    }
    const int l7 = lane & 7;
    float c01 = (l7 & 1) ? zv[1] : zv[0];
    float c23 = (l7 & 1) ? zv[3] : zv[2];
    float c45 = (l7 & 1) ? zv[5] : zv[4];
    float c67 = (l7 & 1) ? zv[7] : zv[6];
    float c03 = (l7 & 2) ? c23 : c01;
    float c47 = (l7 & 2) ? c67 : c45;
    float pk  = (l7 & 4) ? c47 : c03;
    pk += lx<8>(pk);  pk += lx<16>(pk);  pk += lx<32>(pk);
    float z8 = zv[8]; z8 += lx<8>(z8); z8 += lx<16>(z8); z8 += lx<32>(z8);
    float z9 = zv[9]; z9 += lx<8>(z9); z9 += lx<16>(z9); z9 += lx<32>(z9);
    float zsel = pk;
    zsel = (lane == 8) ? z8 : zsel;
    zsel = (lane == 9) ? z9 : zsel;

    // raw z store (fire-and-forget; post-kernel applies C*z + D*a)
    if (lane < NQ) out[(size_t)(b * SEQ + t) * NQ + lane] = zsel;

    // h for next step: lane w's sincos, broadcast via readlane
    float sn_h, cs_h;
    __sincosf(0.5f * zsel, &sn_h, &cs_h);
#pragma unroll
    for (int w = 0; w < NQ; ++w) { hcw[w] = rdl(cs_h, w); hsw[w] = rdl(sn_h, w); }
  }
}

// ---------------- post kernel: out = C*z + D*a, in place ----------------
__global__ __launch_bounds__(256) void qmamba_post(
    const float* __restrict__ angles, const float* __restrict__ Wx,
    const float* __restrict__ Dg, float* __restrict__ out)
{
  int i = blockIdx.x * 256 + threadIdx.x;          // 0 .. 128*512*10-1
  if (i >= NB * SEQ * NQ) return;
  int w  = i % NQ;
  int bt = i / NQ;
  const float* a = angles + (size_t)bt * NQ;
  float C = 0.f;
#pragma unroll
  for (int n = 0; n < NQ; ++n) C += a[n] * Wx[(15 + w) * NQ + n];
  float z = out[i];
  out[i] = C * z + Dg[w] * a[w];
}

extern "C" void kernel_launch(void* const* d_in, const int* in_sizes, int n_in,
                              void* d_out, int out_size, void* d_ws, size_t ws_size,
                              hipStream_t stream) {
  (void)in_sizes; (void)n_in; (void)out_size; (void)d_ws; (void)ws_size;
  const float* angles = (const float*)d_in[0];
  const float* Wx     = (const float*)d_in[1];
  const float* Wdt    = (const float*)d_in[2];
  const float* bdt    = (const float*)d_in[3];
  const float* pc     = (const float*)d_in[4];
  const float* cp     = (const float*)d_in[5];
  const float* Dg     = (const float*)d_in[6];
  float* out = (float*)d_out;
  hipLaunchKernelGGL(qmamba_main, dim3(NB), dim3(NTHR), 0, stream,
                     angles, Wx, Wdt, bdt, pc, cp, out);
  hipLaunchKernelGGL(qmamba_post, dim3((NB * SEQ * NQ + 255) / 256), dim3(256), 0, stream,
                     angles, Wx, Dg, out);
}